// Round 5
// baseline (519.933 us; speedup 1.0000x reference)
//
#include <hip/hip_runtime.h>
#include <math.h>

#define L_SEQ 1024
#define DM 128

// workspace layout (floats)
#define OFF_KHAT 0                         // [L][4][48]  slots: 0..31 K, 32..43 Kg, 44 ck, 45 1.0, 46..47 0
#define OFF_QHAT (L_SEQ * 192)             // [L][4][48]  slots: 0..31 scale*Q, 32..43 w*Qg, 44 1.0, 45 cq
#define OFF_V    (OFF_QHAT + L_SEQ * 192)  // [L][128]    (h*32+d)
#define OFF_VG   (OFF_V + L_SEQ * DM)      // [L][48]     (h*12+p*3+x)

typedef __attribute__((address_space(1))) const void* gas_t;
typedef __attribute__((address_space(3))) void* las_t;

__device__ __forceinline__ void async16(const float4* g, float4* l) {
    __builtin_amdgcn_global_load_lds((gas_t)g, (las_t)l, 16, 0, 0);
}

// ---------------- kernel 1: LN + projections + rotations + staging (1 row/block, grid=1024) ----------------
__global__ __launch_bounds__(256) void ipa_prep(
    const float* __restrict__ single, const float* __restrict__ T,
    const float* __restrict__ w_C, const float* __restrict__ ln_g, const float* __restrict__ ln_b,
    const float* __restrict__ Wq, const float* __restrict__ Wk, const float* __restrict__ Wv,
    const float* __restrict__ Wqpt, const float* __restrict__ Wkpt, const float* __restrict__ Wvpt,
    float* __restrict__ ws)
{
    __shared__ float z_lds[128];
    __shared__ float proj[528];
    __shared__ float qg[4][4][3];
    __shared__ float kg[4][4][3];
    __shared__ float cq[4], ck[4];

    const int t = threadIdx.x;
    const int i = blockIdx.x;

    if (t < 64) {  // wave 0: LayerNorm of row i
        float x0 = single[i*DM + t];
        float x1 = single[i*DM + 64 + t];
        float s = x0 + x1, s2 = x0*x0 + x1*x1;
        #pragma unroll
        for (int off = 1; off < 64; off <<= 1) { s += __shfl_xor(s, off); s2 += __shfl_xor(s2, off); }
        float mu = s * 0.0078125f;
        float var = s2 * 0.0078125f - mu*mu;
        float rs = rsqrtf(var + 1e-5f);
        z_lds[t]      = (x0 - mu) * rs * ln_g[t]      + ln_b[t];
        z_lds[t + 64] = (x1 - mu) * rs * ln_g[t + 64] + ln_b[t + 64];
    }
    __syncthreads();

    for (int cc = t; cc < 528; cc += 256) {
        const float* W; int col, ncol;
        if (cc < 128)      { W = Wq;   col = cc;       ncol = 128; }
        else if (cc < 256) { W = Wk;   col = cc - 128; ncol = 128; }
        else if (cc < 384) { W = Wv;   col = cc - 256; ncol = 128; }
        else if (cc < 432) { W = Wqpt; col = cc - 384; ncol = 48;  }
        else if (cc < 480) { W = Wkpt; col = cc - 432; ncol = 48;  }
        else               { W = Wvpt; col = cc - 480; ncol = 48;  }
        float a = 0.f;
        #pragma unroll 8
        for (int k = 0; k < 128; ++k)
            a = fmaf(z_lds[k], W[k*ncol + col], a);
        proj[cc] = a;
    }
    __syncthreads();

    if (t < 16) {
        int h = t >> 2, p = t & 3;
        float R[3][3], tt[3];
        #pragma unroll
        for (int x = 0; x < 3; ++x) {
            #pragma unroll
            for (int y = 0; y < 3; ++y) R[x][y] = T[i*16 + x*4 + y];
            tt[x] = T[i*16 + x*4 + 3];
        }
        int base = 384 + (h*4 + p)*3;
        float q0 = proj[base],    q1 = proj[base+1],  q2 = proj[base+2];
        float k0 = proj[base+48], k1 = proj[base+49], k2 = proj[base+50];
        float v0 = proj[base+96], v1 = proj[base+97], v2 = proj[base+98];
        #pragma unroll
        for (int x = 0; x < 3; ++x) {
            float qq = R[x][0]*q0 + R[x][1]*q1 + R[x][2]*q2 + tt[x];
            float kk = R[x][0]*k0 + R[x][1]*k1 + R[x][2]*k2 + tt[x];
            float vv = R[x][0]*v0 + R[x][1]*v1 + R[x][2]*v2 + tt[x];
            qg[h][p][x] = qq;
            kg[h][p][x] = kk;
            ws[OFF_VG + (size_t)i*48 + h*12 + p*3 + x] = vv;
        }
    }
    __syncthreads();

    if (t < 8) {
        int h = t >> 1, isk = t & 1;
        float w = w_C[h];
        float wp = log1pf(__expf(w));
        float sq = 0.f;
        #pragma unroll
        for (int p = 0; p < 4; ++p)
            #pragma unroll
            for (int x = 0; x < 3; ++x) {
                float g = isk ? kg[h][p][x] : qg[h][p][x];
                sq += g*g;
            }
        float c = -0.5f * wp * sq;
        if (isk) ck[h] = c; else cq[h] = c;
    }
    __syncthreads();

    if (t < 128) ws[OFF_V + (size_t)i*DM + t] = proj[256 + t];
    const float scale_attn = 0.17677669529663687f;  // 32^-0.5
    if (t < 192) {
        int h = t / 48, k = t % 48;
        float w = w_C[h];
        float wp = log1pf(__expf(w));
        float kv, qv;
        if (k < 32) {
            kv = proj[128 + h*32 + k];
            qv = scale_attn * proj[h*32 + k];
        } else if (k < 44) {
            int e = k - 32;
            kv = kg[h][e/3][e%3];
            qv = wp * qg[h][e/3][e%3];
        } else if (k == 44) { kv = ck[h]; qv = 1.0f; }
        else if (k == 45)   { kv = 1.0f; qv = cq[h]; }
        else                { kv = 0.f;  qv = 0.f; }
        ws[OFF_KHAT + (size_t)i*192 + t] = kv;
        ws[OFF_QHAT + (size_t)i*192 + t] = qv;
    }
}

// ---------------- kernel 2: wave-autonomous flash IPA, 2 rows/block; NO barriers in main loop --------------
// Wave wv owns j-quarter [wv*256, wv*256+256), 16 steps x 16 j, BOTH rows (amortizes kh/v/vg L2 reads,
// doubles independent VALU per latency event). Per-wave LDS pair dbuf, per-wave vmcnt. 5 barriers total.
__global__ __launch_bounds__(256, 2) void ipa_attn(
    const float* __restrict__ single, const float* __restrict__ pair,
    const float* __restrict__ T, const float* __restrict__ Wb,
    const float* __restrict__ Wout, const float* __restrict__ b_out,
    const float* __restrict__ ws, float* __restrict__ out)
{
    // LDS: 65536 + 1664 + 1088 + 2048 = 70336 B -> 2 blocks/CU (grid 512 = 2/CU exactly)
    __shared__ __align__(16) float4 pair_w[4][2][2][16][16]; // [wave][buf][row][j][slot], slot = c4 ^ (j&7)
    __shared__ __align__(16) float4 qhat_lds[2][4][13];      // [row][h][k4] pad 13
    __shared__ __align__(16) float wbt_lds[4][68];           // Wb^T [h][c] pad 68
    __shared__ __align__(16) float p_ws[4][2][16][4];        // [wave][row][j][h]

    const int t = threadIdx.x;
    const int wv = t >> 6, lane = t & 63;
    const int i0 = blockIdx.x * 2;

    if (t < 96) {
        int r = t / 48, rest = t % 48;
        qhat_lds[r][rest/12][rest%12] = ((const float4*)(ws + OFF_QHAT))[(size_t)(i0+r)*48 + rest];
    } else if (t < 160) {
        int c = t - 96;
        float4 w4 = ((const float4*)Wb)[c];   // Wb[c][0..3]
        wbt_lds[0][c] = w4.x; wbt_lds[1][c] = w4.y; wbt_lds[2][c] = w4.z; wbt_lds[3][c] = w4.w;
    }

    // roles within the wave
    const int m_h  = lane & 3,  m_j  = lane >> 2;          // softmax: 16 j x 4 h
    const int os_h = lane >> 4, os_jh = (lane >> 3) & 1, os_d4 = lane & 7;  // o_s
    const int op_c4 = lane & 15, op_jq = lane >> 4;        // o_pair
    const int og_he = lane & 15, og_jq = lane >> 4;        // o_pt_g (he<12 active)
    const bool og_act = og_he < 12;
    const int og_h  = (og_act ? og_he : 0) / 3;
    const int og_ix = og_act ? og_he : 0;

    float m0_run = -INFINITY, l0_run = 0.f;
    float m1_run = -INFINITY, l1_run = 0.f;
    float4 accp[2][4];
    float4 accs[2], accg[2];
    #pragma unroll
    for (int r = 0; r < 2; ++r) {
        accs[r] = make_float4(0.f,0.f,0.f,0.f);
        accg[r] = make_float4(0.f,0.f,0.f,0.f);
        #pragma unroll
        for (int h = 0; h < 4; ++h) accp[r][h] = make_float4(0.f,0.f,0.f,0.f);
    }

    const float4* pair4 = (const float4*)pair;
    const float4* kh4   = (const float4*)(ws + OFF_KHAT);
    const float4* v4    = (const float4*)(ws + OFF_V);
    const float4* vg4   = (const float4*)(ws + OFF_VG);
    float4* mypair = &pair_w[wv][0][0][0][0];   // per wave: 1024 float4 (buf:512, row:256)

    // prologue: stage step 0 -> buf 0 (8 async16/lane: 2 rows x 16 j x 16 slots = 512 float4)
    #pragma unroll
    for (int it = 0; it < 8; ++it) {
        int idx = it*64 + lane;
        int row = idx >> 8, j = (idx >> 4) & 15, slot = idx & 15;
        int c4 = slot ^ (j & 7);
        async16(pair4 + ((size_t)(i0+row)*L_SEQ + wv*256 + j)*16 + c4, mypair + idx);
    }
    __syncthreads();   // qhat/wbt published (note: __syncthreads drains vmcnt too — only a prologue bubble)

    for (int s = 0; s < 16; ++s) {
        const int cur = s & 1;
        const int j0 = wv*256 + s*16;

        // (1) issue ALL of this step's register loads (L2) — consumed after long compute below
        float4 kh[12];
        {
            const float4* kp = kh4 + (size_t)(j0 + m_j)*48 + m_h*12;
            #pragma unroll
            for (int k4 = 0; k4 < 12; ++k4) kh[k4] = kp[k4];
        }
        float4 vv[8];
        #pragma unroll
        for (int jj = 0; jj < 8; ++jj)
            vv[jj] = v4[(size_t)(j0 + os_jh*8 + jj)*32 + os_h*8 + os_d4];
        float4 gvv[4];
        #pragma unroll
        for (int jj = 0; jj < 4; ++jj)
            gvv[jj] = vg4[(size_t)(j0 + og_jq*4 + jj)*12 + og_ix];

        // (2) issue next stage; fence drains ONLY the previous stage (in-order retirement:
        //     12+8+4+8 = 32 issued above the fence; vmcnt(32) retires the 8 older stage ops)
        if (s + 1 < 16) {
            #pragma unroll
            for (int it = 0; it < 8; ++it) {
                int idx = it*64 + lane;
                int row = idx >> 8, j = (idx >> 4) & 15, slot = idx & 15;
                int c4 = slot ^ (j & 7);
                async16(pair4 + ((size_t)(i0+row)*L_SEQ + wv*256 + (s+1)*16 + j)*16 + c4,
                        mypair + (1 - cur)*512 + idx);
            }
            asm volatile("s_waitcnt vmcnt(32)" ::: "memory");
        } else {
            asm volatile("s_waitcnt vmcnt(24)" ::: "memory");
        }

        // (3) bias + logit for both rows, lane = (m_j, m_h)
        const float4* prow0 = mypair + cur*512 +       m_j*16;
        const float4* prow1 = mypair + cur*512 + 256 + m_j*16;
        const float4* wrow  = (const float4*)&wbt_lds[m_h][0];
        float b0 = 0.f, b1 = 0.f;
        #pragma unroll
        for (int cc = 0; cc < 16; ++cc) {
            int sw = cc ^ (m_j & 7);
            float4 wh  = wrow[cc];
            float4 pv0 = prow0[sw];
            float4 pv1 = prow1[sw];
            b0 += pv0.x*wh.x + pv0.y*wh.y + pv0.z*wh.z + pv0.w*wh.w;
            b1 += pv1.x*wh.x + pv1.y*wh.y + pv1.z*wh.z + pv1.w*wh.w;
        }
        float d0a=0.f, d0b=0.f, d1a=0.f, d1b=0.f;
        #pragma unroll
        for (int k4 = 0; k4 < 12; k4 += 2) {
            float4 q0a = qhat_lds[0][m_h][k4], q0b = qhat_lds[0][m_h][k4+1];
            float4 q1a = qhat_lds[1][m_h][k4], q1b = qhat_lds[1][m_h][k4+1];
            float4 ka = kh[k4], kb = kh[k4+1];
            d0a = fmaf(ka.x, q0a.x, d0a); d0a = fmaf(ka.y, q0a.y, d0a);
            d0a = fmaf(ka.z, q0a.z, d0a); d0a = fmaf(ka.w, q0a.w, d0a);
            d0b = fmaf(kb.x, q0b.x, d0b); d0b = fmaf(kb.y, q0b.y, d0b);
            d0b = fmaf(kb.z, q0b.z, d0b); d0b = fmaf(kb.w, q0b.w, d0b);
            d1a = fmaf(ka.x, q1a.x, d1a); d1a = fmaf(ka.y, q1a.y, d1a);
            d1a = fmaf(ka.z, q1a.z, d1a); d1a = fmaf(ka.w, q1a.w, d1a);
            d1b = fmaf(kb.x, q1b.x, d1b); d1b = fmaf(kb.y, q1b.y, d1b);
            d1b = fmaf(kb.z, q1b.z, d1b); d1b = fmaf(kb.w, q1b.w, d1b);
        }
        float logit0 = d0a + d0b + b0;
        float logit1 = d1a + d1b + b1;

        // (4) online softmax, two independent chains (ILP)
        float c0 = logit0, c1 = logit1;
        #pragma unroll
        for (int off = 4; off < 64; off <<= 1) {
            c0 = fmaxf(c0, __shfl_xor(c0, off));
            c1 = fmaxf(c1, __shfl_xor(c1, off));
        }
        float mn0 = fmaxf(m0_run, c0), mn1 = fmaxf(m1_run, c1);
        float al0 = __expf(m0_run - mn0), al1 = __expf(m1_run - mn1);
        float p0 = __expf(logit0 - mn0), p1 = __expf(logit1 - mn1);
        l0_run = l0_run * al0 + p0;  l1_run = l1_run * al1 + p1;
        m0_run = mn0;  m1_run = mn1;
        p_ws[wv][0][m_j][m_h] = p0;
        p_ws[wv][1][m_j][m_h] = p1;
        float a00 = __shfl(al0, 0), a01 = __shfl(al0, 1), a02 = __shfl(al0, 2), a03 = __shfl(al0, 3);
        float a10 = __shfl(al1, 0), a11 = __shfl(al1, 1), a12 = __shfl(al1, 2), a13 = __shfl(al1, 3);
        asm volatile("" ::: "memory");   // order p_ws writes before cross-lane reads (DS in-order per wave)

        // (5) rescale + accumulate
        accp[0][0].x *= a00; accp[0][0].y *= a00; accp[0][0].z *= a00; accp[0][0].w *= a00;
        accp[0][1].x *= a01; accp[0][1].y *= a01; accp[0][1].z *= a01; accp[0][1].w *= a01;
        accp[0][2].x *= a02; accp[0][2].y *= a02; accp[0][2].z *= a02; accp[0][2].w *= a02;
        accp[0][3].x *= a03; accp[0][3].y *= a03; accp[0][3].z *= a03; accp[0][3].w *= a03;
        accp[1][0].x *= a10; accp[1][0].y *= a10; accp[1][0].z *= a10; accp[1][0].w *= a10;
        accp[1][1].x *= a11; accp[1][1].y *= a11; accp[1][1].z *= a11; accp[1][1].w *= a11;
        accp[1][2].x *= a12; accp[1][2].y *= a12; accp[1][2].z *= a12; accp[1][2].w *= a12;
        accp[1][3].x *= a13; accp[1][3].y *= a13; accp[1][3].z *= a13; accp[1][3].w *= a13;
        float as0 = (os_h & 2) ? ((os_h & 1) ? a03 : a02) : ((os_h & 1) ? a01 : a00);
        float as1 = (os_h & 2) ? ((os_h & 1) ? a13 : a12) : ((os_h & 1) ? a11 : a10);
        float ag0 = (og_h & 2) ? ((og_h & 1) ? a03 : a02) : ((og_h & 1) ? a01 : a00);
        float ag1 = (og_h & 2) ? ((og_h & 1) ? a13 : a12) : ((og_h & 1) ? a11 : a10);
        accs[0].x *= as0; accs[0].y *= as0; accs[0].z *= as0; accs[0].w *= as0;
        accs[1].x *= as1; accs[1].y *= as1; accs[1].z *= as1; accs[1].w *= as1;
        accg[0].x *= ag0; accg[0].y *= ag0; accg[0].z *= ag0; accg[0].w *= ag0;
        accg[1].x *= ag1; accg[1].y *= ag1; accg[1].z *= ag1; accg[1].w *= ag1;

        // o_pair: lane (c4, jq), 4 j's x 2 rows
        #pragma unroll
        for (int jj = 0; jj < 4; ++jj) {
            int j = op_jq*4 + jj;
            int sw = op_c4 ^ (j & 7);
            float4 pv0 = mypair[cur*512 +       j*16 + sw];
            float4 pv1 = mypair[cur*512 + 256 + j*16 + sw];
            float4 pj0 = *(const float4*)&p_ws[wv][0][j][0];
            float4 pj1 = *(const float4*)&p_ws[wv][1][j][0];
            accp[0][0].x = fmaf(pj0.x, pv0.x, accp[0][0].x); accp[0][0].y = fmaf(pj0.x, pv0.y, accp[0][0].y);
            accp[0][0].z = fmaf(pj0.x, pv0.z, accp[0][0].z); accp[0][0].w = fmaf(pj0.x, pv0.w, accp[0][0].w);
            accp[0][1].x = fmaf(pj0.y, pv0.x, accp[0][1].x); accp[0][1].y = fmaf(pj0.y, pv0.y, accp[0][1].y);
            accp[0][1].z = fmaf(pj0.y, pv0.z, accp[0][1].z); accp[0][1].w = fmaf(pj0.y, pv0.w, accp[0][1].w);
            accp[0][2].x = fmaf(pj0.z, pv0.x, accp[0][2].x); accp[0][2].y = fmaf(pj0.z, pv0.y, accp[0][2].y);
            accp[0][2].z = fmaf(pj0.z, pv0.z, accp[0][2].z); accp[0][2].w = fmaf(pj0.z, pv0.w, accp[0][2].w);
            accp[0][3].x = fmaf(pj0.w, pv0.x, accp[0][3].x); accp[0][3].y = fmaf(pj0.w, pv0.y, accp[0][3].y);
            accp[0][3].z = fmaf(pj0.w, pv0.z, accp[0][3].z); accp[0][3].w = fmaf(pj0.w, pv0.w, accp[0][3].w);
            accp[1][0].x = fmaf(pj1.x, pv1.x, accp[1][0].x); accp[1][0].y = fmaf(pj1.x, pv1.y, accp[1][0].y);
            accp[1][0].z = fmaf(pj1.x, pv1.z, accp[1][0].z); accp[1][0].w = fmaf(pj1.x, pv1.w, accp[1][0].w);
            accp[1][1].x = fmaf(pj1.y, pv1.x, accp[1][1].x); accp[1][1].y = fmaf(pj1.y, pv1.y, accp[1][1].y);
            accp[1][1].z = fmaf(pj1.y, pv1.z, accp[1][1].z); accp[1][1].w = fmaf(pj1.y, pv1.w, accp[1][1].w);
            accp[1][2].x = fmaf(pj1.z, pv1.x, accp[1][2].x); accp[1][2].y = fmaf(pj1.z, pv1.y, accp[1][2].y);
            accp[1][2].z = fmaf(pj1.z, pv1.z, accp[1][2].z); accp[1][2].w = fmaf(pj1.z, pv1.w, accp[1][2].w);
            accp[1][3].x = fmaf(pj1.w, pv1.x, accp[1][3].x); accp[1][3].y = fmaf(pj1.w, pv1.y, accp[1][3].y);
            accp[1][3].z = fmaf(pj1.w, pv1.z, accp[1][3].z); accp[1][3].w = fmaf(pj1.w, pv1.w, accp[1][3].w);
        }
        // o_s: lane (h, jh, d4), 8 j's x 2 rows (vv shared)
        #pragma unroll
        for (int jj = 0; jj < 8; ++jj) {
            int j = os_jh*8 + jj;
            float pa0 = p_ws[wv][0][j][os_h];
            float pa1 = p_ws[wv][1][j][os_h];
            accs[0].x = fmaf(pa0, vv[jj].x, accs[0].x); accs[0].y = fmaf(pa0, vv[jj].y, accs[0].y);
            accs[0].z = fmaf(pa0, vv[jj].z, accs[0].z); accs[0].w = fmaf(pa0, vv[jj].w, accs[0].w);
            accs[1].x = fmaf(pa1, vv[jj].x, accs[1].x); accs[1].y = fmaf(pa1, vv[jj].y, accs[1].y);
            accs[1].z = fmaf(pa1, vv[jj].z, accs[1].z); accs[1].w = fmaf(pa1, vv[jj].w, accs[1].w);
        }
        // o_pt_g: lane (he, jq), 4 j's x 2 rows (gvv shared)
        #pragma unroll
        for (int jj = 0; jj < 4; ++jj) {
            int j = og_jq*4 + jj;
            float pg0 = og_act ? p_ws[wv][0][j][og_h] : 0.f;
            float pg1 = og_act ? p_ws[wv][1][j][og_h] : 0.f;
            accg[0].x = fmaf(pg0, gvv[jj].x, accg[0].x); accg[0].y = fmaf(pg0, gvv[jj].y, accg[0].y);
            accg[0].z = fmaf(pg0, gvv[jj].z, accg[0].z); accg[0].w = fmaf(pg0, gvv[jj].w, accg[0].w);
            accg[1].x = fmaf(pg1, gvv[jj].x, accg[1].x); accg[1].y = fmaf(pg1, gvv[jj].y, accg[1].y);
            accg[1].z = fmaf(pg1, gvv[jj].z, accg[1].z); accg[1].w = fmaf(pg1, gvv[jj].w, accg[1].w);
        }
    }

    // ---- intra-wave reductions ----
    #pragma unroll
    for (int off = 4; off < 64; off <<= 1) { l0_run += __shfl_xor(l0_run, off); l1_run += __shfl_xor(l1_run, off); }
    #pragma unroll
    for (int r = 0; r < 2; ++r) {
        #pragma unroll
        for (int h = 0; h < 4; ++h) {
            #pragma unroll
            for (int off = 16; off < 64; off <<= 1) {
                accp[r][h].x += __shfl_xor(accp[r][h].x, off);
                accp[r][h].y += __shfl_xor(accp[r][h].y, off);
                accp[r][h].z += __shfl_xor(accp[r][h].z, off);
                accp[r][h].w += __shfl_xor(accp[r][h].w, off);
            }
        }
        accs[r].x += __shfl_xor(accs[r].x, 8); accs[r].y += __shfl_xor(accs[r].y, 8);
        accs[r].z += __shfl_xor(accs[r].z, 8); accs[r].w += __shfl_xor(accs[r].w, 8);
        #pragma unroll
        for (int off = 16; off < 64; off <<= 1) {
            accg[r].x += __shfl_xor(accg[r].x, off); accg[r].y += __shfl_xor(accg[r].y, off);
            accg[r].z += __shfl_xor(accg[r].z, off); accg[r].w += __shfl_xor(accg[r].w, off);
        }
    }

    // ---- publish per-wave partials into own pair region (each wave writes ONLY its region) ----
    float* scratch = (float*)&pair_w[0][0][0][0][0];
    float* cw = scratch + wv*4096;   // wave's 16KB region; rows at r*512, 440 floats each
    #pragma unroll
    for (int r = 0; r < 2; ++r) {
        if (lane < 16) {
            #pragma unroll
            for (int h = 0; h < 4; ++h)
                *(float4*)&cw[r*512 + h*64 + op_c4*4] = accp[r][h];
        }
        if (os_jh == 0) *(float4*)&cw[r*512 + 256 + os_h*32 + os_d4*4] = accs[r];
        if (lane < 12)  *(float4*)&cw[r*512 + 384 + lane*4] = accg[r];
        if (lane < 4) {
            cw[r*512 + 432 + m_h] = (r == 0) ? l0_run : l1_run;
            cw[r*512 + 436 + m_h] = (r == 0) ? m0_run : m1_run;
        }
    }
    __syncthreads();

    // epilogue scratch in wave0's free space [1024, 4096)
    const int EP = 1024;
    float* u   = scratch + EP;          // [2][448]
    float* og2 = scratch + EP + 896;    // [2][48]
    float* wts = scratch + EP + 992;    // [2][16]  wt[r][w*4+h]
    float* ivs = scratch + EP + 1024;   // [2][4]

    if (t < 8) {
        int r = t >> 2, h = t & 3;
        float m0 = scratch[0*4096 + r*512 + 436 + h], m1 = scratch[1*4096 + r*512 + 436 + h];
        float m2 = scratch[2*4096 + r*512 + 436 + h], m3 = scratch[3*4096 + r*512 + 436 + h];
        float M = fmaxf(fmaxf(m0, m1), fmaxf(m2, m3));
        float w0 = __expf(m0 - M), w1 = __expf(m1 - M);
        float w2 = __expf(m2 - M), w3 = __expf(m3 - M);
        float L = scratch[0*4096 + r*512 + 432 + h]*w0 + scratch[1*4096 + r*512 + 432 + h]*w1
                + scratch[2*4096 + r*512 + 432 + h]*w2 + scratch[3*4096 + r*512 + 432 + h]*w3;
        wts[r*16 + 0 + h] = w0; wts[r*16 + 4 + h] = w1;
        wts[r*16 + 8 + h] = w2; wts[r*16 + 12 + h] = w3;
        ivs[r*4 + h] = 1.f / L;
    }
    __syncthreads();

    {
        int r = t >> 7, q = t & 127;
        const float* wt = wts + r*16;
        const float* iv = ivs + r*4;
        // o_s (128/row)
        {
            int hs = q >> 5;
            float v = scratch[0*4096 + r*512 + 256 + q]*wt[0 + hs] + scratch[1*4096 + r*512 + 256 + q]*wt[4 + hs]
                    + scratch[2*4096 + r*512 + 256 + q]*wt[8 + hs] + scratch[3*4096 + r*512 + 256 + q]*wt[12 + hs];
            u[r*448 + q] = v * iv[hs];
        }
        // o_pair (256/row)
        #pragma unroll
        for (int pp = 0; pp < 2; ++pp) {
            int idx = pp*128 + q;
            int hp = idx >> 6;
            float v = scratch[0*4096 + r*512 + idx]*wt[0 + hp] + scratch[1*4096 + r*512 + idx]*wt[4 + hp]
                    + scratch[2*4096 + r*512 + idx]*wt[8 + hp] + scratch[3*4096 + r*512 + idx]*wt[12 + hp];
            u[r*448 + 128 + idx] = v * iv[hp];
        }
        // o_pt_g (48/row)
        if (t < 96) {
            int r2 = t / 48, qg = t % 48, hg = qg / 12;
            const float* wt2 = wts + r2*16;
            float v = scratch[0*4096 + r2*512 + 384 + qg]*wt2[0 + hg] + scratch[1*4096 + r2*512 + 384 + qg]*wt2[4 + hg]
                    + scratch[2*4096 + r2*512 + 384 + qg]*wt2[8 + hg] + scratch[3*4096 + r2*512 + 384 + qg]*wt2[12 + hg];
            og2[r2*48 + qg] = v * ivs[r2*4 + hg];
        }
    }
    __syncthreads();

    if (t < 32) {
        int r = t >> 4, idx = t & 15, h = idx >> 2, p = idx & 3;
        int ii = i0 + r;
        float R[3][3], tt[3];
        #pragma unroll
        for (int x = 0; x < 3; ++x) {
            #pragma unroll
            for (int y = 0; y < 3; ++y) R[x][y] = T[ii*16 + x*4 + y];
            tt[x] = T[ii*16 + x*4 + 3];
        }
        float v0 = og2[r*48 + h*12 + p*3+0] - tt[0];
        float v1 = og2[r*48 + h*12 + p*3+1] - tt[1];
        float v2 = og2[r*48 + h*12 + p*3+2] - tt[2];
        float n2 = 0.f;
        #pragma unroll
        for (int x = 0; x < 3; ++x) {
            float o = R[0][x]*v0 + R[1][x]*v1 + R[2][x]*v2;
            u[r*448 + 384 + h*12 + p*3 + x] = o;
            n2 += o*o;
        }
        u[r*448 + 432 + h*4 + p] = sqrtf(n2);
    }
    __syncthreads();

    // final matmul: thread -> (row, d)
    {
        int r = t >> 7, d = t & 127;
        int ii = i0 + r;
        float acc = single[ii*DM + d] + b_out[d];
        const float4* u4 = (const float4*)(u + r*448);
        #pragma unroll 4
        for (int k4 = 0; k4 < 112; ++k4) {
            float4 uu = u4[k4];
            const float* wp = Wout + (size_t)(k4*4)*128 + d;
            acc = fmaf(uu.x, wp[0],   acc);
            acc = fmaf(uu.y, wp[128], acc);
            acc = fmaf(uu.z, wp[256], acc);
            acc = fmaf(uu.w, wp[384], acc);
        }
        out[ii*DM + d] = acc;
    }
}

extern "C" void kernel_launch(void* const* d_in, const int* in_sizes, int n_in,
                              void* d_out, int out_size, void* d_ws, size_t ws_size,
                              hipStream_t stream)
{
    const float* single = (const float*)d_in[0];
    const float* pair   = (const float*)d_in[1];
    const float* T      = (const float*)d_in[2];
    const float* w_C    = (const float*)d_in[3];
    const float* ln_g   = (const float*)d_in[4];
    const float* ln_b   = (const float*)d_in[5];
    const float* Wq     = (const float*)d_in[6];
    const float* Wk     = (const float*)d_in[7];
    const float* Wv     = (const float*)d_in[8];
    const float* Wqpt   = (const float*)d_in[9];
    const float* Wkpt   = (const float*)d_in[10];
    const float* Wvpt   = (const float*)d_in[11];
    const float* Wb     = (const float*)d_in[12];
    const float* Wout   = (const float*)d_in[13];
    const float* b_out  = (const float*)d_in[14];
    float* out = (float*)d_out;
    float* ws  = (float*)d_ws;

    ipa_prep<<<1024, 256, 0, stream>>>(single, T, w_C, ln_g, ln_b, Wq, Wk, Wv, Wqpt, Wkpt, Wvpt, ws);
    ipa_attn<<<512, 256, 0, stream>>>(single, pair, T, Wb, Wout, b_out, ws, out);
}